// Round 10
// baseline (36.051 us; speedup 1.0000x reference)
//
#include <hip/hip_runtime.h>

#define NC 20            // classes (fixed by problem)
#define NP 100           // probes
#define PG 20            // probes per cdf block (was 10: halves E re-reads)
#define NPG (NP / PG)    // 5 probe-groups
#define SLICES 20        // n-slices -> grid 20*5*20 = 2000 blocks (co-resident)
#define TPB 256
#define KLOG2E 14.426950408889634f   // TEMPERATURE * log2(e)
#define NBS 256          // partial-array stride (max prep blocks.x)

__device__ __forceinline__ float fexp2(float x) {
#if __has_builtin(__builtin_amdgcn_exp2f)
    return __builtin_amdgcn_exp2f(x);
#else
    return __builtin_exp2f(x);
#endif
}
__device__ __forceinline__ float sgpr_f(float x) {
    return __uint_as_float(__builtin_amdgcn_readfirstlane(__float_as_uint(x)));
}

// Kernel A (prep): grid (nb, 5). Block covers 256 rows x 4 classes (q = class quad).
// Writes Es[c][n] = (s[n] ? -1 : +1) * 2^(K*pred)  (group bit in SIGN; pads +inf),
// per-block partial min/max/count to unique slots, zeroes the (c,pg) counters.
template<bool WRITE_T>
__global__ __launch_bounds__(256)
void prep_kernel(const float* __restrict__ y, const int* __restrict__ s,
                 float* __restrict__ E,
                 float* __restrict__ part_mn, float* __restrict__ part_mx,
                 int* __restrict__ part_cnt, unsigned* __restrict__ cntCP,
                 int N, int ncap) {
    const int q = blockIdx.y;          // classes 4q .. 4q+3
    const int bx = blockIdx.x;
    // re-zero the fused-finalize counters every call (plain store; kernel-end release)
    if (q == 2 && bx == 0 && threadIdx.x < NC * NPG) cntCP[threadIdx.x] = 0u;

    float mn[4] = {3.4e38f, 3.4e38f, 3.4e38f, 3.4e38f};
    float mx[4] = {-3.4e38f, -3.4e38f, -3.4e38f, -3.4e38f};
    int cnt = 0;
    const int stride = gridDim.x * 256;
    for (int n = bx * 256 + threadIdx.x; n < ncap; n += stride) {
        if (n < N) {
            float4 f = ((const float4*)y)[n * 5 + q];   // y[n][4q..4q+3]
            float v[4] = {f.x, f.y, f.z, f.w};
            if (q == 0) cnt += s[n];
            unsigned sgn = 0u;
            if (WRITE_T) sgn = (s[n] ? 0x80000000u : 0u);
#pragma unroll
            for (int cc = 0; cc < 4; ++cc) {
                mn[cc] = fminf(mn[cc], v[cc]);
                mx[cc] = fmaxf(mx[cc], v[cc]);
                if (WRITE_T) {
                    float e = fexp2(v[cc] * KLOG2E);
                    E[(size_t)(4 * q + cc) * ncap + n] =
                        __uint_as_float(__float_as_uint(e) | sgn);
                }
            }
        } else if (WRITE_T) {
#pragma unroll
            for (int cc = 0; cc < 4; ++cc)
                E[(size_t)(4 * q + cc) * ncap + n] = __builtin_inff();  // inert pad
        }
    }
#pragma unroll
    for (int off = 1; off < 64; off <<= 1) {
#pragma unroll
        for (int cc = 0; cc < 4; ++cc) {
            mn[cc] = fminf(mn[cc], __shfl_xor(mn[cc], off));
            mx[cc] = fmaxf(mx[cc], __shfl_xor(mx[cc], off));
        }
        cnt += __shfl_xor(cnt, off);
    }
    __shared__ float smn[4][4], smx[4][4];
    __shared__ int scnt[4];
    const int wave = threadIdx.x >> 6, lane = threadIdx.x & 63;
    if (lane == 0) {
#pragma unroll
        for (int cc = 0; cc < 4; ++cc) { smn[wave][cc] = mn[cc]; smx[wave][cc] = mx[cc]; }
        scnt[wave] = cnt;
    }
    __syncthreads();
    const int t = threadIdx.x;
    if (t < 4) {
        part_mn[(4 * q + t) * NBS + bx] =
            fminf(fminf(smn[0][t], smn[1][t]), fminf(smn[2][t], smn[3][t]));
    } else if (t < 8) {
        int cc = t - 4;
        part_mx[(4 * q + cc) * NBS + bx] =
            fmaxf(fmaxf(smx[0][cc], smx[1][cc]), fmaxf(smx[2][cc], smx[3][cc]));
    } else if (t == 8 && q == 0) {
        part_cnt[bx] = scnt[0] + scnt[1] + scnt[2] + scnt[3];
    }
}

// Kernel B (cdf2 + distributed fused finalize): block = (c, pg, z).
// Inner loop: t = fma(|Es|, G, 1); r = rcp(t); d = fma(r, w, d), w from sign(Es).
// Slots via relaxed AGENT atomic stores; per-(c,pg) relaxed counter;
// last slice block reloads PG*SLICES slots and atomicMax's into out.
template<bool RAW>
__global__ __launch_bounds__(256)
void cdf2_kernel(const float* __restrict__ E,
                 const float* __restrict__ y, const int* __restrict__ s,
                 const float* __restrict__ part_mn, const float* __restrict__ part_mx,
                 const int* __restrict__ part_cnt,
                 float* __restrict__ acc_part, unsigned* __restrict__ cntCP,
                 float* __restrict__ out, int N, int ncap, int nb) {
    const int c = blockIdx.x;
    const int pg = blockIdx.y;
    // stage-2 reduce of prep partials for this class + n1 count
    float lmn = 3.4e38f, lmx = -3.4e38f;
    int lcnt = 0;
    for (int t = threadIdx.x; t < nb; t += 256) {
        lmn = fminf(lmn, part_mn[c * NBS + t]);
        lmx = fmaxf(lmx, part_mx[c * NBS + t]);
        lcnt += part_cnt[t];
    }
#pragma unroll
    for (int off = 1; off < 64; off <<= 1) {
        lmn = fminf(lmn, __shfl_xor(lmn, off));
        lmx = fmaxf(lmx, __shfl_xor(lmx, off));
        lcnt += __shfl_xor(lcnt, off);
    }
    __shared__ float rmn[4], rmx[4];
    __shared__ int rcnt[4];
    const int wave = threadIdx.x >> 6, lane = threadIdx.x & 63;
    if (lane == 0) { rmn[wave] = lmn; rmx[wave] = lmx; rcnt[wave] = lcnt; }
    __syncthreads();
    const float mn = fminf(fminf(rmn[0], rmn[1]), fminf(rmn[2], rmn[3]));
    const float mx = fmaxf(fmaxf(rmx[0], rmx[1]), fmaxf(rmx[2], rmx[3]));
    const int n1 = rcnt[0] + rcnt[1] + rcnt[2] + rcnt[3];
    const float inv1 = 1.0f / (float)n1;
    const float inv0 = 1.0f / (float)(N - n1);
    const float sA1 = sgpr_f(inv1);          // group1: w = +1/n1
    const float sB  = sgpr_f(-inv0);         // group0: w = -1/n0

    // G_j = 2^(-K*g_j): lane j computes probe pg*PG+j, broadcast to SGPRs
    int p = pg * PG + (lane % PG);
    float frac = (float)p / 99.0f;                  // matches reference fp32 divide
    float g = fmaf(mx - mn, frac, mn);
    float Gl = fexp2(-g * KLOG2E);
    float G[PG];
#pragma unroll
    for (int j = 0; j < PG; ++j) G[j] = sgpr_f(__shfl(Gl, j));

    float d[PG];
#pragma unroll
    for (int j = 0; j < PG; ++j) d[j] = 0.f;

    const int nq = ncap >> 2;
    if (!RAW) {
        const float4* E4 = (const float4*)(E + (size_t)c * ncap);
#pragma unroll 2
        for (int q = blockIdx.z * TPB + threadIdx.x; q < nq; q += TPB * SLICES) {
            float4 ev = E4[q];
            float ee[4] = {ev.x, ev.y, ev.z, ev.w};
            float ww[4];
#pragma unroll
            for (int e = 0; e < 4; ++e)    // sign bit = group1 flag
                ww[e] = (__float_as_int(ee[e]) < 0) ? sA1 : sB;
#pragma unroll
            for (int e = 0; e < 4; ++e) {
#pragma unroll
                for (int j = 0; j < PG; ++j) {
                    float t = fmaf(fabsf(ee[e]), G[j], 1.0f);  // |Es| free modifier
                    float r = __builtin_amdgcn_rcpf(t);        // sigmoid
                    d[j] = fmaf(r, ww[e], d[j]);
                }
            }
        }
    } else {
        for (int q = blockIdx.z * TPB + threadIdx.x; q < nq; q += TPB * SLICES) {
#pragma unroll
            for (int e = 0; e < 4; ++e) {
                int n = q * 4 + e;
                bool valid = n < N;
                float ev = valid ? fexp2(y[(size_t)n * NC + c] * KLOG2E)
                                 : __builtin_inff();
                float w  = valid ? ((s[n] != 0) ? sA1 : sB) : 0.f;
#pragma unroll
                for (int j = 0; j < PG; ++j) {
                    float t = fmaf(ev, G[j], 1.0f);
                    float r = __builtin_amdgcn_rcpf(t);
                    d[j] = fmaf(r, w, d[j]);
                }
            }
        }
    }
    // block reduce: wave butterfly -> LDS -> slot (relaxed agent atomic store)
#pragma unroll
    for (int off = 1; off < 64; off <<= 1) {
#pragma unroll
        for (int j = 0; j < PG; ++j) d[j] += __shfl_xor(d[j], off);
    }
    __shared__ float sd[4][PG];
    if (lane == 0) {
#pragma unroll
        for (int j = 0; j < PG; ++j) sd[wave][j] = d[j];
    }
    __syncthreads();
    float* slot_base = acc_part + (size_t)(c * NPG + pg) * PG * SLICES;
    if (threadIdx.x < PG) {
        int j = threadIdx.x;
        float v = (sd[0][j] + sd[1][j]) + (sd[2][j] + sd[3][j]);
        __hip_atomic_store(slot_base + j * SLICES + blockIdx.z, v,
                           __ATOMIC_RELAXED, __HIP_MEMORY_SCOPE_AGENT);
    }
    // order: slot stores must be ack'd at the coherence point before the count
    asm volatile("s_waitcnt vmcnt(0)" ::: "memory");
    __shared__ int is_last;
    if (threadIdx.x == 0) {
        unsigned prev = __hip_atomic_fetch_add(&cntCP[c * NPG + pg], 1u,
                                               __ATOMIC_RELAXED,
                                               __HIP_MEMORY_SCOPE_AGENT);
        is_last = (prev == SLICES - 1);
    }
    __syncthreads();
    if (!is_last) return;

    // last slice block of this (c,pg): reduce its PG*SLICES slots, one atomicMax
    __shared__ float sval[PG * SLICES];
    for (int i = threadIdx.x; i < PG * SLICES; i += 256)
        sval[i] = __hip_atomic_load(slot_base + i, __ATOMIC_RELAXED,
                                    __HIP_MEMORY_SCOPE_AGENT);
    __syncthreads();
    float m = 0.f;
    if (threadIdx.x < PG) {
        float sum = 0.f;
#pragma unroll
        for (int z = 0; z < SLICES; ++z) sum += sval[threadIdx.x * SLICES + z];
        m = fabsf(sum);
    }
    if (wave == 0) {
#pragma unroll
        for (int off = 1; off < 32; off <<= 1)
            m = fmaxf(m, __shfl_xor(m, off));
        if (lane == 0)
            atomicMax((int*)out, __float_as_int(m));   // m >= 0; idempotent
    }
}

extern "C" void kernel_launch(void* const* d_in, const int* in_sizes, int n_in,
                              void* d_out, int out_size, void* d_ws, size_t ws_size,
                              hipStream_t stream) {
    const float* y = (const float*)d_in[0];
    const int* s   = (const int*)d_in[1];
    const int N = in_sizes[1];
    const int ncap = ((N + 1023) / 1024) * 1024;
    int nb = ncap / 256;
    if (nb > NBS) nb = NBS;

    unsigned char* ws = (unsigned char*)d_ws;
    float* part_mn  = (float*)ws;                   // [NC][NBS]  @0      (20480 B)
    float* part_mx  = (float*)(ws + 20480);         // [NC][NBS]  @20480  (20480 B)
    int*   part_cnt = (int*)  (ws + 40960);         // [NBS]      @40960  (1024 B)
    unsigned* cntCP = (unsigned*)(ws + 43008);      // [NC*NPG]   @43008  (400 B)
    float* acc_part = (float*)(ws + 45056);         // [NC*NP][SLICES] (160000 B)
    float* E        = (float*)(ws + 262144);        // [NC][ncap] signed-packed
    size_t need = 262144 + (size_t)4 * NC * ncap;
    bool fat = ws_size >= need;

    dim3 gA(nb, 5);
    if (fat) prep_kernel<true ><<<gA, 256, 0, stream>>>(y, s, E, part_mn, part_mx, part_cnt, cntCP, N, ncap);
    else     prep_kernel<false><<<gA, 256, 0, stream>>>(y, s, nullptr, part_mn, part_mx, part_cnt, cntCP, N, ncap);

    dim3 gB(NC, NPG, SLICES);
    if (fat) cdf2_kernel<false><<<gB, 256, 0, stream>>>(E, y, s, part_mn, part_mx, part_cnt, acc_part, cntCP, (float*)d_out, N, ncap, nb);
    else     cdf2_kernel<true ><<<gB, 256, 0, stream>>>(nullptr, y, s, part_mn, part_mx, part_cnt, acc_part, cntCP, (float*)d_out, N, ncap, nb);
}

// Round 11
// 33.669 us; speedup vs baseline: 1.0707x; 1.0707x over previous
//
#include <hip/hip_runtime.h>

#define NC 20            // classes (fixed by problem)
#define NP 100           // probes
#define PG 10            // probes per cdf block (PG=20 regressed in R10)
#define NPG (NP / PG)    // 10 probe-groups
#define SLICES 10        // n-slices -> grid 20*10*10 = 2000 blocks (co-resident)
#define TPB 256
#define KLOG2E 14.426950408889634f   // TEMPERATURE * log2(e)
#define NBS 256          // partial-array stride (max prep blocks.x)
#define TCLAMP 9.223372e18f          // 2^63: keeps t_a*t_b finite; sig<=2^-63~0

__device__ __forceinline__ float fexp2(float x) {
#if __has_builtin(__builtin_amdgcn_exp2f)
    return __builtin_amdgcn_exp2f(x);
#else
    return __builtin_exp2f(x);
#endif
}
__device__ __forceinline__ float sgpr_f(float x) {
    return __uint_as_float(__builtin_amdgcn_readfirstlane(__float_as_uint(x)));
}

// Kernel A (prep): grid (nb, 5). Block covers 256 rows x 4 classes (q = class quad).
// Writes Es[c][n] = (s[n] ? -1 : +1) * 2^(K*pred)  (group bit in SIGN; pads +inf),
// per-block partial min/max/count to unique slots, zeroes the (c,pg) counters.
template<bool WRITE_T>
__global__ __launch_bounds__(256)
void prep_kernel(const float* __restrict__ y, const int* __restrict__ s,
                 float* __restrict__ E,
                 float* __restrict__ part_mn, float* __restrict__ part_mx,
                 int* __restrict__ part_cnt, unsigned* __restrict__ cntCP,
                 int N, int ncap) {
    const int q = blockIdx.y;          // classes 4q .. 4q+3
    const int bx = blockIdx.x;
    // re-zero the fused-finalize counters every call (plain store; kernel-end release)
    if (q == 2 && bx == 0 && threadIdx.x < NC * NPG) cntCP[threadIdx.x] = 0u;

    float mn[4] = {3.4e38f, 3.4e38f, 3.4e38f, 3.4e38f};
    float mx[4] = {-3.4e38f, -3.4e38f, -3.4e38f, -3.4e38f};
    int cnt = 0;
    const int stride = gridDim.x * 256;
    for (int n = bx * 256 + threadIdx.x; n < ncap; n += stride) {
        if (n < N) {
            float4 f = ((const float4*)y)[n * 5 + q];   // y[n][4q..4q+3]
            float v[4] = {f.x, f.y, f.z, f.w};
            if (q == 0) cnt += s[n];
            unsigned sgn = 0u;
            if (WRITE_T) sgn = (s[n] ? 0x80000000u : 0u);
#pragma unroll
            for (int cc = 0; cc < 4; ++cc) {
                mn[cc] = fminf(mn[cc], v[cc]);
                mx[cc] = fmaxf(mx[cc], v[cc]);
                if (WRITE_T) {
                    float e = fexp2(v[cc] * KLOG2E);
                    E[(size_t)(4 * q + cc) * ncap + n] =
                        __uint_as_float(__float_as_uint(e) | sgn);
                }
            }
        } else if (WRITE_T) {
#pragma unroll
            for (int cc = 0; cc < 4; ++cc)
                E[(size_t)(4 * q + cc) * ncap + n] = __builtin_inff();  // inert pad
        }
    }
#pragma unroll
    for (int off = 1; off < 64; off <<= 1) {
#pragma unroll
        for (int cc = 0; cc < 4; ++cc) {
            mn[cc] = fminf(mn[cc], __shfl_xor(mn[cc], off));
            mx[cc] = fmaxf(mx[cc], __shfl_xor(mx[cc], off));
        }
        cnt += __shfl_xor(cnt, off);
    }
    __shared__ float smn[4][4], smx[4][4];
    __shared__ int scnt[4];
    const int wave = threadIdx.x >> 6, lane = threadIdx.x & 63;
    if (lane == 0) {
#pragma unroll
        for (int cc = 0; cc < 4; ++cc) { smn[wave][cc] = mn[cc]; smx[wave][cc] = mx[cc]; }
        scnt[wave] = cnt;
    }
    __syncthreads();
    const int t = threadIdx.x;
    if (t < 4) {
        part_mn[(4 * q + t) * NBS + bx] =
            fminf(fminf(smn[0][t], smn[1][t]), fminf(smn[2][t], smn[3][t]));
    } else if (t < 8) {
        int cc = t - 4;
        part_mx[(4 * q + cc) * NBS + bx] =
            fmaxf(fmaxf(smx[0][cc], smx[1][cc]), fmaxf(smx[2][cc], smx[3][cc]));
    } else if (t == 8 && q == 0) {
        part_cnt[bx] = scnt[0] + scnt[1] + scnt[2] + scnt[3];
    }
}

// Kernel B (cdf2 + distributed fused finalize): block = (c, pg, z).
// Pair-reciprocal inner loop: one v_rcp per TWO elem-probes:
//   ta=min(fma(|ea|,G,1),2^63); tb=...; r=rcp(ta*tb); d+=r*tb*wa; d+=r*ta*wb.
// Slots via relaxed AGENT atomic stores; per-(c,pg) relaxed counter;
// last slice block reloads PG*SLICES slots and atomicMax's into out.
template<bool RAW>
__global__ __launch_bounds__(256)
void cdf2_kernel(const float* __restrict__ E,
                 const float* __restrict__ y, const int* __restrict__ s,
                 const float* __restrict__ part_mn, const float* __restrict__ part_mx,
                 const int* __restrict__ part_cnt,
                 float* __restrict__ acc_part, unsigned* __restrict__ cntCP,
                 float* __restrict__ out, int N, int ncap, int nb) {
    const int c = blockIdx.x;
    const int pg = blockIdx.y;
    // stage-2 reduce of prep partials for this class + n1 count
    float lmn = 3.4e38f, lmx = -3.4e38f;
    int lcnt = 0;
    for (int t = threadIdx.x; t < nb; t += 256) {
        lmn = fminf(lmn, part_mn[c * NBS + t]);
        lmx = fmaxf(lmx, part_mx[c * NBS + t]);
        lcnt += part_cnt[t];
    }
#pragma unroll
    for (int off = 1; off < 64; off <<= 1) {
        lmn = fminf(lmn, __shfl_xor(lmn, off));
        lmx = fmaxf(lmx, __shfl_xor(lmx, off));
        lcnt += __shfl_xor(lcnt, off);
    }
    __shared__ float rmn[4], rmx[4];
    __shared__ int rcnt[4];
    const int wave = threadIdx.x >> 6, lane = threadIdx.x & 63;
    if (lane == 0) { rmn[wave] = lmn; rmx[wave] = lmx; rcnt[wave] = lcnt; }
    __syncthreads();
    const float mn = fminf(fminf(rmn[0], rmn[1]), fminf(rmn[2], rmn[3]));
    const float mx = fmaxf(fmaxf(rmx[0], rmx[1]), fmaxf(rmx[2], rmx[3]));
    const int n1 = rcnt[0] + rcnt[1] + rcnt[2] + rcnt[3];
    const float inv1 = 1.0f / (float)n1;
    const float inv0 = 1.0f / (float)(N - n1);
    const float sA1 = sgpr_f(inv1);          // group1: w = +1/n1
    const float sB  = sgpr_f(-inv0);         // group0: w = -1/n0

    // G_j = 2^(-K*g_j): lane j computes probe pg*PG+j, broadcast to SGPRs
    int p = pg * PG + (lane % PG);
    float frac = (float)p / 99.0f;                  // matches reference fp32 divide
    float g = fmaf(mx - mn, frac, mn);
    float Gl = fexp2(-g * KLOG2E);
    float G[PG];
#pragma unroll
    for (int j = 0; j < PG; ++j) G[j] = sgpr_f(__shfl(Gl, j));

    float d[PG];
#pragma unroll
    for (int j = 0; j < PG; ++j) d[j] = 0.f;

    const int nq = ncap >> 2;
    if (!RAW) {
        const float4* E4 = (const float4*)(E + (size_t)c * ncap);
#pragma unroll 2
        for (int q = blockIdx.z * TPB + threadIdx.x; q < nq; q += TPB * SLICES) {
            float4 ev = E4[q];
            float ea[4], ww[4];
            ea[0] = fabsf(ev.x); ea[1] = fabsf(ev.y);
            ea[2] = fabsf(ev.z); ea[3] = fabsf(ev.w);
            ww[0] = (__float_as_int(ev.x) < 0) ? sA1 : sB;
            ww[1] = (__float_as_int(ev.y) < 0) ? sA1 : sB;
            ww[2] = (__float_as_int(ev.z) < 0) ? sA1 : sB;
            ww[3] = (__float_as_int(ev.w) < 0) ? sA1 : sB;
#pragma unroll
            for (int pr = 0; pr < 2; ++pr) {           // element pairs (0,1),(2,3)
                float eA = ea[2 * pr], eB = ea[2 * pr + 1];
                float wA = ww[2 * pr], wB = ww[2 * pr + 1];
#pragma unroll
                for (int j = 0; j < PG; ++j) {
                    float ta = fminf(fmaf(eA, G[j], 1.0f), TCLAMP);
                    float tb = fminf(fmaf(eB, G[j], 1.0f), TCLAMP);
                    float r = __builtin_amdgcn_rcpf(ta * tb);  // one rcp / 2 elems
                    d[j] = fmaf(r * tb, wA, d[j]);             // sig_a = r*tb
                    d[j] = fmaf(r * ta, wB, d[j]);             // sig_b = r*ta
                }
            }
        }
    } else {
        for (int q = blockIdx.z * TPB + threadIdx.x; q < nq; q += TPB * SLICES) {
#pragma unroll
            for (int e = 0; e < 4; ++e) {
                int n = q * 4 + e;
                bool valid = n < N;
                float ev = valid ? fexp2(y[(size_t)n * NC + c] * KLOG2E)
                                 : __builtin_inff();
                float w  = valid ? ((s[n] != 0) ? sA1 : sB) : 0.f;
#pragma unroll
                for (int j = 0; j < PG; ++j) {
                    float t = fminf(fmaf(ev, G[j], 1.0f), TCLAMP);
                    float r = __builtin_amdgcn_rcpf(t);
                    d[j] = fmaf(r, w, d[j]);
                }
            }
        }
    }
    // block reduce: wave butterfly -> LDS -> slot (relaxed agent atomic store)
#pragma unroll
    for (int off = 1; off < 64; off <<= 1) {
#pragma unroll
        for (int j = 0; j < PG; ++j) d[j] += __shfl_xor(d[j], off);
    }
    __shared__ float sd[4][PG];
    if (lane == 0) {
#pragma unroll
        for (int j = 0; j < PG; ++j) sd[wave][j] = d[j];
    }
    __syncthreads();
    float* slot_base = acc_part + (size_t)(c * NPG + pg) * PG * SLICES;
    if (threadIdx.x < PG) {
        int j = threadIdx.x;
        float v = (sd[0][j] + sd[1][j]) + (sd[2][j] + sd[3][j]);
        __hip_atomic_store(slot_base + j * SLICES + blockIdx.z, v,
                           __ATOMIC_RELAXED, __HIP_MEMORY_SCOPE_AGENT);
    }
    // order: slot stores must be ack'd at the coherence point before the count
    asm volatile("s_waitcnt vmcnt(0)" ::: "memory");
    __shared__ int is_last;
    if (threadIdx.x == 0) {
        unsigned prev = __hip_atomic_fetch_add(&cntCP[c * NPG + pg], 1u,
                                               __ATOMIC_RELAXED,
                                               __HIP_MEMORY_SCOPE_AGENT);
        is_last = (prev == SLICES - 1);
    }
    __syncthreads();
    if (!is_last) return;

    // last slice block of this (c,pg): reduce its PG*SLICES slots, one atomicMax
    __shared__ float sval[PG * SLICES];
    for (int i = threadIdx.x; i < PG * SLICES; i += 256)
        sval[i] = __hip_atomic_load(slot_base + i, __ATOMIC_RELAXED,
                                    __HIP_MEMORY_SCOPE_AGENT);
    __syncthreads();
    float m = 0.f;
    if (threadIdx.x < PG) {
        float sum = 0.f;
#pragma unroll
        for (int z = 0; z < SLICES; ++z) sum += sval[threadIdx.x * SLICES + z];
        m = fabsf(sum);
    }
    if (wave == 0) {
#pragma unroll
        for (int off = 1; off < 32; off <<= 1)
            m = fmaxf(m, __shfl_xor(m, off));
        if (lane == 0)
            atomicMax((int*)out, __float_as_int(m));   // m >= 0; idempotent
    }
}

extern "C" void kernel_launch(void* const* d_in, const int* in_sizes, int n_in,
                              void* d_out, int out_size, void* d_ws, size_t ws_size,
                              hipStream_t stream) {
    const float* y = (const float*)d_in[0];
    const int* s   = (const int*)d_in[1];
    const int N = in_sizes[1];
    const int ncap = ((N + 1023) / 1024) * 1024;
    int nb = ncap / 256;
    if (nb > NBS) nb = NBS;

    unsigned char* ws = (unsigned char*)d_ws;
    float* part_mn  = (float*)ws;                   // [NC][NBS]  @0      (20480 B)
    float* part_mx  = (float*)(ws + 20480);         // [NC][NBS]  @20480  (20480 B)
    int*   part_cnt = (int*)  (ws + 40960);         // [NBS]      @40960  (1024 B)
    unsigned* cntCP = (unsigned*)(ws + 43008);      // [NC*NPG]   @43008  (800 B)
    float* acc_part = (float*)(ws + 45056);         // [NC*NP][SLICES] (80000 B)
    float* E        = (float*)(ws + 131072);        // [NC][ncap] signed-packed
    size_t need = 131072 + (size_t)4 * NC * ncap;
    bool fat = ws_size >= need;

    dim3 gA(nb, 5);
    if (fat) prep_kernel<true ><<<gA, 256, 0, stream>>>(y, s, E, part_mn, part_mx, part_cnt, cntCP, N, ncap);
    else     prep_kernel<false><<<gA, 256, 0, stream>>>(y, s, nullptr, part_mn, part_mx, part_cnt, cntCP, N, ncap);

    dim3 gB(NC, NPG, SLICES);
    if (fat) cdf2_kernel<false><<<gB, 256, 0, stream>>>(E, y, s, part_mn, part_mx, part_cnt, acc_part, cntCP, (float*)d_out, N, ncap, nb);
    else     cdf2_kernel<true ><<<gB, 256, 0, stream>>>(nullptr, y, s, part_mn, part_mx, part_cnt, acc_part, cntCP, (float*)d_out, N, ncap, nb);
}

// Round 12
// 31.423 us; speedup vs baseline: 1.1473x; 1.0715x over previous
//
#include <hip/hip_runtime.h>

#define NC 20            // classes (fixed by problem)
#define NP 100           // probes
#define PG 10            // probes per cdf block
#define NPG (NP / PG)    // 10 probe-groups
#define SLICES 10        // n-slices -> grid 20*10*10 = 2000 blocks (co-resident)
#define TPB 256
#define KLOG2E 14.426950408889634f   // TEMPERATURE * log2(e)
#define NBS 256          // partial-array stride (max prep blocks.x)
#define QSTRIDE (TPB * SLICES)       // quad stride per iteration

__device__ __forceinline__ float fexp2(float x) {
#if __has_builtin(__builtin_amdgcn_exp2f)
    return __builtin_amdgcn_exp2f(x);
#else
    return __builtin_exp2f(x);
#endif
}
__device__ __forceinline__ float sgpr_f(float x) {
    return __uint_as_float(__builtin_amdgcn_readfirstlane(__float_as_uint(x)));
}

// Kernel A (prep): grid (nb, 5). Block covers 256 rows x 4 classes (q = class quad).
// Writes Es[c][n] = (s[n] ? -1 : +1) * 2^(K*pred)  (group bit in SIGN; pads +inf),
// per-block partial min/max/count to unique slots, zeroes the (c,pg) counters.
template<bool WRITE_T>
__global__ __launch_bounds__(256)
void prep_kernel(const float* __restrict__ y, const int* __restrict__ s,
                 float* __restrict__ E,
                 float* __restrict__ part_mn, float* __restrict__ part_mx,
                 int* __restrict__ part_cnt, unsigned* __restrict__ cntCP,
                 int N, int ncap) {
    const int q = blockIdx.y;          // classes 4q .. 4q+3
    const int bx = blockIdx.x;
    // re-zero the fused-finalize counters every call (plain store; kernel-end release)
    if (q == 2 && bx == 0 && threadIdx.x < NC * NPG) cntCP[threadIdx.x] = 0u;

    float mn[4] = {3.4e38f, 3.4e38f, 3.4e38f, 3.4e38f};
    float mx[4] = {-3.4e38f, -3.4e38f, -3.4e38f, -3.4e38f};
    int cnt = 0;
    const int stride = gridDim.x * 256;
    for (int n = bx * 256 + threadIdx.x; n < ncap; n += stride) {
        if (n < N) {
            float4 f = ((const float4*)y)[n * 5 + q];   // y[n][4q..4q+3]
            float v[4] = {f.x, f.y, f.z, f.w};
            if (q == 0) cnt += s[n];
            unsigned sgn = 0u;
            if (WRITE_T) sgn = (s[n] ? 0x80000000u : 0u);
#pragma unroll
            for (int cc = 0; cc < 4; ++cc) {
                mn[cc] = fminf(mn[cc], v[cc]);
                mx[cc] = fmaxf(mx[cc], v[cc]);
                if (WRITE_T) {
                    float e = fexp2(v[cc] * KLOG2E);
                    E[(size_t)(4 * q + cc) * ncap + n] =
                        __uint_as_float(__float_as_uint(e) | sgn);
                }
            }
        } else if (WRITE_T) {
#pragma unroll
            for (int cc = 0; cc < 4; ++cc)
                E[(size_t)(4 * q + cc) * ncap + n] = __builtin_inff();  // inert pad
        }
    }
#pragma unroll
    for (int off = 1; off < 64; off <<= 1) {
#pragma unroll
        for (int cc = 0; cc < 4; ++cc) {
            mn[cc] = fminf(mn[cc], __shfl_xor(mn[cc], off));
            mx[cc] = fmaxf(mx[cc], __shfl_xor(mx[cc], off));
        }
        cnt += __shfl_xor(cnt, off);
    }
    __shared__ float smn[4][4], smx[4][4];
    __shared__ int scnt[4];
    const int wave = threadIdx.x >> 6, lane = threadIdx.x & 63;
    if (lane == 0) {
#pragma unroll
        for (int cc = 0; cc < 4; ++cc) { smn[wave][cc] = mn[cc]; smx[wave][cc] = mx[cc]; }
        scnt[wave] = cnt;
    }
    __syncthreads();
    const int t = threadIdx.x;
    if (t < 4) {
        part_mn[(4 * q + t) * NBS + bx] =
            fminf(fminf(smn[0][t], smn[1][t]), fminf(smn[2][t], smn[3][t]));
    } else if (t < 8) {
        int cc = t - 4;
        part_mx[(4 * q + cc) * NBS + bx] =
            fmaxf(fmaxf(smx[0][cc], smx[1][cc]), fmaxf(smx[2][cc], smx[3][cc]));
    } else if (t == 8 && q == 0) {
        part_cnt[bx] = scnt[0] + scnt[1] + scnt[2] + scnt[3];
    }
}

// Kernel B (cdf2 + distributed fused finalize): block = (c, pg, z).
// T>0: compile-time trip count -> all T float4 loads issued before compute.
// Inner: t = fma(|Es|, G, 1); r = rcp(t); d = fma(r, w, d), w from sign(Es).
template<bool RAW, int T>
__global__ __launch_bounds__(256)
void cdf2_kernel(const float* __restrict__ E,
                 const float* __restrict__ y, const int* __restrict__ s,
                 const float* __restrict__ part_mn, const float* __restrict__ part_mx,
                 const int* __restrict__ part_cnt,
                 float* __restrict__ acc_part, unsigned* __restrict__ cntCP,
                 float* __restrict__ out, int N, int ncap, int nb) {
    const int c = blockIdx.x;
    const int pg = blockIdx.y;
    // stage-2 reduce of prep partials for this class + n1 count
    float lmn = 3.4e38f, lmx = -3.4e38f;
    int lcnt = 0;
    for (int t = threadIdx.x; t < nb; t += 256) {
        lmn = fminf(lmn, part_mn[c * NBS + t]);
        lmx = fmaxf(lmx, part_mx[c * NBS + t]);
        lcnt += part_cnt[t];
    }
#pragma unroll
    for (int off = 1; off < 64; off <<= 1) {
        lmn = fminf(lmn, __shfl_xor(lmn, off));
        lmx = fmaxf(lmx, __shfl_xor(lmx, off));
        lcnt += __shfl_xor(lcnt, off);
    }
    __shared__ float rmn[4], rmx[4];
    __shared__ int rcnt[4];
    const int wave = threadIdx.x >> 6, lane = threadIdx.x & 63;
    if (lane == 0) { rmn[wave] = lmn; rmx[wave] = lmx; rcnt[wave] = lcnt; }
    __syncthreads();
    const float mn = fminf(fminf(rmn[0], rmn[1]), fminf(rmn[2], rmn[3]));
    const float mx = fmaxf(fmaxf(rmx[0], rmx[1]), fmaxf(rmx[2], rmx[3]));
    const int n1 = rcnt[0] + rcnt[1] + rcnt[2] + rcnt[3];
    const float inv1 = 1.0f / (float)n1;
    const float inv0 = 1.0f / (float)(N - n1);
    const float sA1 = sgpr_f(inv1);          // group1: w = +1/n1
    const float sB  = sgpr_f(-inv0);         // group0: w = -1/n0

    // G_j = 2^(-K*g_j): lane j computes probe pg*PG+j, broadcast to SGPRs
    int p = pg * PG + (lane % PG);
    float frac = (float)p / 99.0f;                  // matches reference fp32 divide
    float g = fmaf(mx - mn, frac, mn);
    float Gl = fexp2(-g * KLOG2E);
    float G[PG];
#pragma unroll
    for (int j = 0; j < PG; ++j) G[j] = sgpr_f(__shfl(Gl, j));

    float d[PG];
#pragma unroll
    for (int j = 0; j < PG; ++j) d[j] = 0.f;

    const int nq = ncap >> 2;
    if (!RAW) {
        const float4* E4 = (const float4*)(E + (size_t)c * ncap);
        const int q0 = blockIdx.z * TPB + threadIdx.x;
        if (T > 0) {
            // exact trip count: issue ALL loads first (max MLP), then compute
            constexpr int TT = (T > 0) ? T : 1;
            float4 ev[TT];
#pragma unroll
            for (int it = 0; it < TT; ++it) ev[it] = E4[q0 + it * QSTRIDE];
#pragma unroll
            for (int it = 0; it < TT; ++it) {
                float ee[4] = {ev[it].x, ev[it].y, ev[it].z, ev[it].w};
#pragma unroll
                for (int e = 0; e < 4; ++e) {
                    float w = (__float_as_int(ee[e]) < 0) ? sA1 : sB;
                    float ea = fabsf(ee[e]);
#pragma unroll
                    for (int j = 0; j < PG; ++j) {
                        float t = fmaf(ea, G[j], 1.0f);       // 1 + E*G (inf-safe)
                        float r = __builtin_amdgcn_rcpf(t);   // sigmoid
                        d[j] = fmaf(r, w, d[j]);
                    }
                }
            }
        } else {
#pragma unroll 2
            for (int q = q0; q < nq; q += QSTRIDE) {
                float4 ev = E4[q];
                float ee[4] = {ev.x, ev.y, ev.z, ev.w};
#pragma unroll
                for (int e = 0; e < 4; ++e) {
                    float w = (__float_as_int(ee[e]) < 0) ? sA1 : sB;
                    float ea = fabsf(ee[e]);
#pragma unroll
                    for (int j = 0; j < PG; ++j) {
                        float t = fmaf(ea, G[j], 1.0f);
                        float r = __builtin_amdgcn_rcpf(t);
                        d[j] = fmaf(r, w, d[j]);
                    }
                }
            }
        }
    } else {
        for (int q = blockIdx.z * TPB + threadIdx.x; q < nq; q += QSTRIDE) {
#pragma unroll
            for (int e = 0; e < 4; ++e) {
                int n = q * 4 + e;
                bool valid = n < N;
                float ev = valid ? fexp2(y[(size_t)n * NC + c] * KLOG2E)
                                 : __builtin_inff();
                float w  = valid ? ((s[n] != 0) ? sA1 : sB) : 0.f;
#pragma unroll
                for (int j = 0; j < PG; ++j) {
                    float t = fmaf(ev, G[j], 1.0f);
                    float r = __builtin_amdgcn_rcpf(t);
                    d[j] = fmaf(r, w, d[j]);
                }
            }
        }
    }
    // block reduce: wave butterfly -> LDS -> slot (relaxed agent atomic store)
#pragma unroll
    for (int off = 1; off < 64; off <<= 1) {
#pragma unroll
        for (int j = 0; j < PG; ++j) d[j] += __shfl_xor(d[j], off);
    }
    __shared__ float sd[4][PG];
    if (lane == 0) {
#pragma unroll
        for (int j = 0; j < PG; ++j) sd[wave][j] = d[j];
    }
    __syncthreads();
    float* slot_base = acc_part + (size_t)(c * NPG + pg) * PG * SLICES;
    if (threadIdx.x < PG) {
        int j = threadIdx.x;
        float v = (sd[0][j] + sd[1][j]) + (sd[2][j] + sd[3][j]);
        __hip_atomic_store(slot_base + j * SLICES + blockIdx.z, v,
                           __ATOMIC_RELAXED, __HIP_MEMORY_SCOPE_AGENT);
    }
    // order: slot stores must be ack'd at the coherence point before the count
    asm volatile("s_waitcnt vmcnt(0)" ::: "memory");
    __shared__ int is_last;
    if (threadIdx.x == 0) {
        unsigned prev = __hip_atomic_fetch_add(&cntCP[c * NPG + pg], 1u,
                                               __ATOMIC_RELAXED,
                                               __HIP_MEMORY_SCOPE_AGENT);
        is_last = (prev == SLICES - 1);
    }
    __syncthreads();
    if (!is_last) return;

    // last slice block of this (c,pg): reduce its PG*SLICES slots, one atomicMax
    __shared__ float sval[PG * SLICES];
    for (int i = threadIdx.x; i < PG * SLICES; i += 256)
        sval[i] = __hip_atomic_load(slot_base + i, __ATOMIC_RELAXED,
                                    __HIP_MEMORY_SCOPE_AGENT);
    __syncthreads();
    float m = 0.f;
    if (threadIdx.x < PG) {
        float sum = 0.f;
#pragma unroll
        for (int z = 0; z < SLICES; ++z) sum += sval[threadIdx.x * SLICES + z];
        m = fabsf(sum);
    }
    if (wave == 0) {
#pragma unroll
        for (int off = 1; off < 32; off <<= 1)
            m = fmaxf(m, __shfl_xor(m, off));
        if (lane == 0)
            atomicMax((int*)out, __float_as_int(m));   // m >= 0; idempotent
    }
}

extern "C" void kernel_launch(void* const* d_in, const int* in_sizes, int n_in,
                              void* d_out, int out_size, void* d_ws, size_t ws_size,
                              hipStream_t stream) {
    const float* y = (const float*)d_in[0];
    const int* s   = (const int*)d_in[1];
    const int N = in_sizes[1];
    // pad so nq = ncap/4 divides evenly into TPB*SLICES -> exact trip count
    const int ncap = ((N + 4 * QSTRIDE - 1) / (4 * QSTRIDE)) * (4 * QSTRIDE);
    const int trip = ncap / (4 * QSTRIDE);
    int nb = ncap / 256;
    if (nb > NBS) nb = NBS;

    unsigned char* ws = (unsigned char*)d_ws;
    float* part_mn  = (float*)ws;                   // [NC][NBS]  @0      (20480 B)
    float* part_mx  = (float*)(ws + 20480);         // [NC][NBS]  @20480  (20480 B)
    int*   part_cnt = (int*)  (ws + 40960);         // [NBS]      @40960  (1024 B)
    unsigned* cntCP = (unsigned*)(ws + 43008);      // [NC*NPG]   @43008  (800 B)
    float* acc_part = (float*)(ws + 45056);         // [NC*NP][SLICES] (80000 B)
    float* E        = (float*)(ws + 131072);        // [NC][ncap] signed-packed
    size_t need = 131072 + (size_t)4 * NC * ncap;
    bool fat = ws_size >= need;

    dim3 gA(nb, 5);
    if (fat) prep_kernel<true ><<<gA, 256, 0, stream>>>(y, s, E, part_mn, part_mx, part_cnt, cntCP, N, ncap);
    else     prep_kernel<false><<<gA, 256, 0, stream>>>(y, s, nullptr, part_mn, part_mx, part_cnt, cntCP, N, ncap);

    dim3 gB(NC, NPG, SLICES);
    if (fat) {
        if      (trip == 5) cdf2_kernel<false, 5><<<gB, 256, 0, stream>>>(E, y, s, part_mn, part_mx, part_cnt, acc_part, cntCP, (float*)d_out, N, ncap, nb);
        else if (trip == 4) cdf2_kernel<false, 4><<<gB, 256, 0, stream>>>(E, y, s, part_mn, part_mx, part_cnt, acc_part, cntCP, (float*)d_out, N, ncap, nb);
        else if (trip == 6) cdf2_kernel<false, 6><<<gB, 256, 0, stream>>>(E, y, s, part_mn, part_mx, part_cnt, acc_part, cntCP, (float*)d_out, N, ncap, nb);
        else                cdf2_kernel<false, 0><<<gB, 256, 0, stream>>>(E, y, s, part_mn, part_mx, part_cnt, acc_part, cntCP, (float*)d_out, N, ncap, nb);
    } else {
        cdf2_kernel<true, 0><<<gB, 256, 0, stream>>>(nullptr, y, s, part_mn, part_mx, part_cnt, acc_part, cntCP, (float*)d_out, N, ncap, nb);
    }
}